// Round 1
// baseline (2575.598 us; speedup 1.0000x reference)
//
#include <hip/hip_runtime.h>

// Problem constants (B=8, Cin=O=16, group=12, H=64)
#define NB   8
#define NIC  192        // Cin*12
#define NOC  192        // O*12
#define HP   66
#define WP   322
#define HO   64
#define WO   320

// Expanded hex kernel: [ic][oc][8] (tap 0..6 used, tap7 = 0 pad), ~1.18 MB
__device__ float g_Kexp[NIC * NOC * 8];

// ---------------------------------------------------------------------------
// Kernel 1: expand weight (O,Cin,12,7) -> Kexp[ic][oc][8] using group tables.
// perm[g][h] = compose(inv(g), h);  tap_src[g][i] per reference.
// ---------------------------------------------------------------------------
__global__ void prep_kernel(const float* __restrict__ w) {
    int tid = blockIdx.x * 256 + threadIdx.x;
    if (tid >= NIC * NOC) return;
    int oc = tid / NIC, ic = tid - (tid / NIC) * NIC;
    int o = oc / 12, g = oc % 12;
    int c = ic / 12, h = ic % 12;
    int f = g / 6, r = g % 6;
    int ri = (f == 0) ? (6 - r) % 6 : r;          // inv(g).r  (inv(g).f == f)
    int fh = h / 6, rh = h % 6;
    int pf = f ^ fh;
    int pr = (f == 0) ? (ri + rh) % 6 : (ri - rh + 6) % 6;
    int pm = pf * 6 + pr;                          // perm[g][h]
    const float* wsrc = w + ((o * 16 + c) * 12 + pm) * 7;
    float* dst = g_Kexp + ((size_t)ic * NOC + oc) * 8;
    dst[0] = wsrc[0];                              // tap_src[g][0] = 0
#pragma unroll
    for (int i = 0; i < 6; i++) {
        int src = (f == 0) ? (i - r + 6) % 6 : (r - i + 6) % 6;
        dst[1 + i] = wsrc[1 + src];
    }
    dst[7] = 0.f;
}

// ---------------------------------------------------------------------------
// Kernel 2: direct conv, interior only. Writes d_out[b][oc][1+py][1+px].
// Hex taps (tap i -> (hy,hx)): 0:(1,1) 1:(0,0) 2:(0,1) 3:(1,2) 4:(2,2)
//                              5:(2,1) 6:(1,0)
// Block 256 = 16(tx: pixel groups) x 16(ty: oc groups); thread tile 4 oc x 4 px.
// Block tile: 64 pixels (one row segment) x 64 oc. IC chunked by 8 via LDS.
// ---------------------------------------------------------------------------
__global__ __launch_bounds__(256) void conv_kernel(
    const float* __restrict__ x, const float* __restrict__ bias,
    float* __restrict__ out) {
    __shared__ __align__(16) float xs[8][3][68];   // [icc][row][col], col pad 68
    __shared__ __align__(16) float ws[8][64][8];   // [icc][oc_local][tap]

    int pix = blockIdx.x;                 // 0..2559 = b*64*5 tiles
    int oc0 = blockIdx.y * 64;            // 0,64,128
    int xt = pix % 5;
    int py = (pix / 5) % 64;
    int b  = pix / (5 * 64);
    int px0 = xt * 64;

    int tid = threadIdx.x;
    int tx = tid & 15, ty = tid >> 4;
    int tx4 = tx * 4;

    float acc[4][4] = {};                 // [oc q][pixel p]
    const float* xb = x + (size_t)b * NIC * HP * WP;

    for (int ic0 = 0; ic0 < NIC; ic0 += 8) {
        // ---- stage x tile: 8 ic x 3 rows x 66 cols ----
        for (int fidx = tid; fidx < 8 * 3 * 66; fidx += 256) {
            int icc = fidx / 198;
            int rem = fidx - icc * 198;
            int row = rem / 66;
            int col = rem - row * 66;
            xs[icc][row][col] =
                xb[(size_t)(ic0 + icc) * HP * WP + (py + row) * WP + px0 + col];
        }
        // ---- stage weights: 8 ic x 64 oc x 8 taps = 1024 float4 ----
        for (int fidx = tid; fidx < 1024; fidx += 256) {
            int icc = fidx >> 7;          // /128
            int off = fidx & 127;
            ((float4*)ws)[icc * 128 + off] =
                *(const float4*)(g_Kexp +
                                 ((size_t)(ic0 + icc) * NOC + oc0) * 8 + off * 4);
        }
        __syncthreads();

#pragma unroll
        for (int icc = 0; icc < 8; icc++) {
            float xr0[6], xr1[6], xr2[6];
            *(float4*)&xr0[0] = *(const float4*)&xs[icc][0][tx4];
            *(float2*)&xr0[4] = *(const float2*)&xs[icc][0][tx4 + 4];
            *(float4*)&xr1[0] = *(const float4*)&xs[icc][1][tx4];
            *(float2*)&xr1[4] = *(const float2*)&xs[icc][1][tx4 + 4];
            *(float4*)&xr2[0] = *(const float4*)&xs[icc][2][tx4];
            *(float2*)&xr2[4] = *(const float2*)&xs[icc][2][tx4 + 4];
#pragma unroll
            for (int q = 0; q < 4; q++) {
                const float* wq = &ws[icc][ty * 4 + q][0];
                float4 wa = *(const float4*)wq;
                float4 wb = *(const float4*)(wq + 4);
                // wa = taps 0..3, wb.x..wb.z = taps 4..6
#pragma unroll
                for (int p = 0; p < 4; p++) {
                    acc[q][p] += xr0[p]     * wa.y   // tap1 (0,0)
                               + xr0[p + 1] * wa.z   // tap2 (0,1)
                               + xr1[p]     * wb.z   // tap6 (1,0)
                               + xr1[p + 1] * wa.x   // tap0 (1,1)
                               + xr1[p + 2] * wa.w   // tap3 (1,2)
                               + xr2[p + 1] * wb.y   // tap5 (2,1)
                               + xr2[p + 2] * wb.x;  // tap4 (2,2)
                }
            }
        }
        __syncthreads();
    }

    // ---- epilogue: +bias, write interior of d_out ----
#pragma unroll
    for (int q = 0; q < 4; q++) {
        int oc = oc0 + ty * 4 + q;
        float bv = bias[oc / 12];
        size_t base = ((size_t)(b * NOC + oc) * HP + (py + 1)) * WP
                      + (px0 + tx4 + 1);
#pragma unroll
        for (int p = 0; p < 4; p++) out[base + p] = acc[q][p] + bv;
    }
}

// ---------------------------------------------------------------------------
// Kernel 3: fill the 1-px ring via twisted-periodic gather from interior.
// 772 ring pixels per (b,channel); source is always interior (already written).
// ---------------------------------------------------------------------------
__global__ void border_kernel(float* __restrict__ out) {
    int tid = blockIdx.x * 256 + threadIdx.x;   // < 8*192*772 = 1185792
    int r  = tid % 772;
    int bc = tid / 772;
    int ch = bc % NOC;
    int b  = bc / NOC;
    int y, xx;
    if (r < 322)      { y = 0;  xx = r; }
    else if (r < 644) { y = 65; xx = r - 322; }
    else if (r < 708) { xx = 0;   y = r - 644 + 1; }
    else              { xx = 321; y = r - 708 + 1; }
    int t = ch % 12;
    int o12 = ch - t;
    int f = t / 6, rr = t % 6;
    int dt = (xx == 0) ? 1 : ((xx == 321) ? -1 : 0);
    int sx = (xx == 0) ? 320 : ((xx == 321) ? 1 : xx);
    int sy = (y == 0) ? 64 : ((y == 65) ? 1 : y);
    int tsrc = f * 6 + (rr + dt + 6) % 6;
    float v = out[((size_t)(b * NOC + o12 + tsrc) * HP + sy) * WP + sx];
    out[((size_t)(b * NOC + ch) * HP + y) * WP + xx] = v;
}

extern "C" void kernel_launch(void* const* d_in, const int* in_sizes, int n_in,
                              void* d_out, int out_size, void* d_ws, size_t ws_size,
                              hipStream_t stream) {
    const float* x    = (const float*)d_in[0];
    const float* w    = (const float*)d_in[1];
    const float* bias = (const float*)d_in[2];
    float* out = (float*)d_out;

    prep_kernel<<<(NIC * NOC + 255) / 256, 256, 0, stream>>>(w);
    dim3 grid(NB * 64 * 5, 3);            // 2560 pixel tiles x 3 oc tiles
    conv_kernel<<<grid, 256, 0, stream>>>(x, bias, out);
    border_kernel<<<(NB * NOC * 772) / 256, 256, 0, stream>>>(out);
}

// Round 2
// 465.856 us; speedup vs baseline: 5.5287x; 5.5287x over previous
//
#include <hip/hip_runtime.h>

// Problem constants (B=8, Cin=O=16, group=12, H=64)
#define NB   8
#define NIC  192        // Cin*12
#define NOC  192        // O*12
#define HP   66
#define WP   322

typedef _Float16 f16x8 __attribute__((ext_vector_type(8)));
typedef float    f32x4 __attribute__((ext_vector_type(4)));

// Expanded hex-tap weights, f16, layout [tap][oc][ic]  (7*192*192*2B = 516 KB)
__device__ _Float16 g_K16[7 * NOC * NIC];

// ---------------------------------------------------------------------------
// Kernel 1: expand weight (O,Cin,12,7) -> g_K16[tap][oc][ic] (f16)
// ---------------------------------------------------------------------------
__global__ void prep_kernel(const float* __restrict__ w) {
    int tid = blockIdx.x * 256 + threadIdx.x;
    if (tid >= 7 * NOC * NIC) return;
    int ic = tid % NIC;
    int rest = tid / NIC;
    int oc = rest % NOC;
    int t = rest / NOC;
    int o = oc / 12, g = oc % 12;
    int c = ic / 12, h = ic % 12;
    int f = g / 6, r = g % 6;
    int ri = (f == 0) ? (6 - r) % 6 : r;          // inv(g).r
    int fh = h / 6, rh = h % 6;
    int pf = f ^ fh;
    int pr = (f == 0) ? (ri + rh) % 6 : (ri - rh + 6) % 6;
    int pm = pf * 6 + pr;                          // perm[g][h]
    const float* wsrc = w + ((o * 16 + c) * 12 + pm) * 7;
    float v;
    if (t == 0) {
        v = wsrc[0];
    } else {
        int i = t - 1;
        int s = (f == 0) ? (i - r + 6) % 6 : (r - i + 6) % 6;
        v = wsrc[1 + s];
    }
    g_K16[tid] = (_Float16)v;
}

// ---------------------------------------------------------------------------
// Kernel 2: MFMA implicit-GEMM conv over 7 hex taps.
// Block C-tile: 192 oc x 128 pixels (2 output rows x 64 cols), K chunk = 32 ic.
// 4 waves: (wm = pixel-row, wn = oc-half); wave tile 96 oc x 64 px.
// Hex taps (hy,hx): 0:(1,1) 1:(0,0) 2:(0,1) 3:(1,2) 4:(2,2) 5:(2,1) 6:(1,0)
// ---------------------------------------------------------------------------
__global__ __launch_bounds__(256) void conv_kernel(
    const float* __restrict__ x, const float* __restrict__ bias,
    float* __restrict__ out) {
    __shared__ __align__(16) _Float16 xs[4 * 66 * 32];      // [row][col][ic] 16.9KB
    __shared__ __align__(16) _Float16 wsb[2 * NOC * 32];    // dbuf [oc][ic]  24.6KB

    int id = blockIdx.x;                  // 1280 blocks
    int xt = id % 5;
    int yt = (id / 5) % 32;
    int b  = id / 160;
    int px0 = xt * 64, py0 = yt * 2;

    int tid = threadIdx.x;
    int wave = tid >> 6;
    int lane = tid & 63;
    int kg = lane >> 4, n15 = lane & 15;
    int wm = wave & 1;                    // pixel-row half (output row py0+1+wm)
    int wn = wave >> 1;                   // oc half (wn*96)

    const int HY[7] = {1, 0, 0, 1, 2, 2, 1};
    const int HX[7] = {1, 0, 1, 2, 2, 1, 0};

    const float* xb = x + (size_t)b * (NIC * HP * WP);

    f32x4 acc[6][4] = {};                 // [oc group][pixel group]

    int buf = 0;
    for (int ic0 = 0; ic0 < NIC; ic0 += 32) {
        // ---- stage xs: 4 rows x 66 cols x 32 ic, transposed to ic-innermost ----
        {
            const float* xrow = xb + (size_t)ic0 * (HP * WP) + (size_t)py0 * WP + px0;
#pragma unroll
            for (int f2 = 0; f2 < 33; f2++) {           // 8448 / 256
                int idx = tid + f2 * 256;
                int icc = idx / 264;                     // 264 = 4*66
                int rem = idx - icc * 264;
                int row = rem / 66;
                int col = rem - row * 66;
                float v = xrow[(size_t)icc * (HP * WP) + row * WP + col];
                xs[(row * 66 + col) * 32 + icc] = (_Float16)v;
            }
        }
        // ---- stage weights tap 0 into wsb[buf] ----
        {
            const _Float16* ksrc = g_K16 + ic0;          // tap 0
#pragma unroll
            for (int f2 = 0; f2 < 3; f2++) {             // 768 float4 / 256
                int idx = tid + f2 * 256;
                int oc = idx >> 2, seg = idx & 3;
                *(float4*)&wsb[buf * 6144 + oc * 32 + seg * 8] =
                    *(const float4*)&ksrc[oc * NIC + seg * 8];
            }
        }
        __syncthreads();

#pragma unroll
        for (int t = 0; t < 7; t++) {
            // prefetch next tap's weights into the other buffer
            if (t < 6) {
                int nb = buf ^ 1;
                const _Float16* ksrc = g_K16 + (size_t)(t + 1) * NOC * NIC + ic0;
#pragma unroll
                for (int f2 = 0; f2 < 3; f2++) {
                    int idx = tid + f2 * 256;
                    int oc = idx >> 2, seg = idx & 3;
                    *(float4*)&wsb[nb * 6144 + oc * 32 + seg * 8] =
                        *(const float4*)&ksrc[oc * NIC + seg * 8];
                }
            }
            // compute: A = weights (M=oc), B = x (N=pixels)
            int ab = buf * 6144 + (wn * 96 + n15) * 32 + kg * 8;
            int bb = ((wm + HY[t]) * 66 + n15 + HX[t]) * 32 + kg * 8;
            f16x8 xf[4];
#pragma unroll
            for (int ni = 0; ni < 4; ni++)
                xf[ni] = *(const f16x8*)&xs[bb + ni * 512];   // ni*16*32
#pragma unroll
            for (int mi = 0; mi < 6; mi++) {
                f16x8 wf = *(const f16x8*)&wsb[ab + mi * 512];
#pragma unroll
                for (int ni = 0; ni < 4; ni++)
                    acc[mi][ni] = __builtin_amdgcn_mfma_f32_16x16x32_f16(
                        wf, xf[ni], acc[mi][ni], 0, 0, 0);
            }
            __syncthreads();
            buf ^= 1;
        }
    }

    // ---- epilogue: +bias, write interior rows (coalesced 64B runs per lane-group) ----
    int yo = py0 + 1 + wm;
#pragma unroll
    for (int mi = 0; mi < 6; mi++) {
#pragma unroll
        for (int reg = 0; reg < 4; reg++) {
            int oc = wn * 96 + mi * 16 + kg * 4 + reg;
            float bv = bias[oc / 12];
            size_t base = ((size_t)(b * NOC + oc) * HP + yo) * WP + 1 + px0 + n15;
#pragma unroll
            for (int ni = 0; ni < 4; ni++)
                out[base + ni * 16] = acc[mi][ni][reg] + bv;
        }
    }
}

// ---------------------------------------------------------------------------
// Kernel 3: fill the 1-px ring via twisted-periodic gather from interior.
// ---------------------------------------------------------------------------
__global__ void border_kernel(float* __restrict__ out) {
    int tid = blockIdx.x * 256 + threadIdx.x;   // < 8*192*772 = 1185792
    int r  = tid % 772;
    int bc = tid / 772;
    int ch = bc % NOC;
    int b  = bc / NOC;
    int y, xx;
    if (r < 322)      { y = 0;  xx = r; }
    else if (r < 644) { y = 65; xx = r - 322; }
    else if (r < 708) { xx = 0;   y = r - 644 + 1; }
    else              { xx = 321; y = r - 708 + 1; }
    int t = ch % 12;
    int o12 = ch - t;
    int f = t / 6, rr = t % 6;
    int dt = (xx == 0) ? 1 : ((xx == 321) ? -1 : 0);
    int sx = (xx == 0) ? 320 : ((xx == 321) ? 1 : xx);
    int sy = (y == 0) ? 64 : ((y == 65) ? 1 : y);
    int tsrc = f * 6 + (rr + dt + 6) % 6;
    float v = out[((size_t)(b * NOC + o12 + tsrc) * HP + sy) * WP + sx];
    out[((size_t)(b * NOC + ch) * HP + y) * WP + xx] = v;
}

extern "C" void kernel_launch(void* const* d_in, const int* in_sizes, int n_in,
                              void* d_out, int out_size, void* d_ws, size_t ws_size,
                              hipStream_t stream) {
    const float* x    = (const float*)d_in[0];
    const float* w    = (const float*)d_in[1];
    const float* bias = (const float*)d_in[2];
    float* out = (float*)d_out;

    prep_kernel<<<(7 * NOC * NIC) / 256, 256, 0, stream>>>(w);
    conv_kernel<<<1280, 256, 0, stream>>>(x, bias, out);
    border_kernel<<<(NB * NOC * 772) / 256, 256, 0, stream>>>(out);
}

// Round 4
// 419.606 us; speedup vs baseline: 6.1381x; 1.1102x over previous
//
#include <hip/hip_runtime.h>

// Problem constants (B=8, Cin=O=16, group=12, H=64)
#define NB   8
#define NIC  192        // Cin*12
#define NOC  192        // O*12
#define HP   66
#define WP   322
#define HPWP (HP * WP)

typedef _Float16 f16x8 __attribute__((ext_vector_type(8)));
typedef float    f32x4 __attribute__((ext_vector_type(4)));

// Swizzled weights: [icc6][tap7][kg4][oc192][j8]  (516 KB)
__device__ __align__(16) _Float16 g_Ks[6 * 7 * 4 * 192 * 8];
// Transposed f16 x: [b8][icc6][y66][col322][ic32]  (65.3 MB)
__device__ __align__(16) _Float16 g_xt[NB * 6 * 66 * 322 * 32];

// ---------------------------------------------------------------------------
// Kernel 1: expand weight (O,Cin,12,7) -> g_Ks (f16, MFMA-A-swizzled)
// ---------------------------------------------------------------------------
__global__ void prep_kernel(const float* __restrict__ w) {
    int tid = blockIdx.x * 256 + threadIdx.x;
    if (tid >= 7 * NOC * NIC) return;
    int ic = tid % NIC;
    int rest = tid / NIC;
    int oc = rest % NOC;
    int t = rest / NOC;
    int o = oc / 12, g = oc % 12;
    int c = ic / 12, h = ic % 12;
    int f = g / 6, r = g % 6;
    int ri = (f == 0) ? (6 - r) % 6 : r;          // inv(g).r
    int fh = h / 6, rh = h % 6;
    int pf = f ^ fh;
    int pr = (f == 0) ? (ri + rh) % 6 : (ri - rh + 6) % 6;
    int pm = pf * 6 + pr;                          // perm[g][h]
    const float* wsrc = w + ((o * 16 + c) * 12 + pm) * 7;
    float v;
    if (t == 0) {
        v = wsrc[0];
    } else {
        int i = t - 1;
        int s = (f == 0) ? (i - r + 6) % 6 : (r - i + 6) % 6;
        v = wsrc[1 + s];
    }
    int icc = ic >> 5, kg = (ic >> 3) & 3, j = ic & 7;
    g_Ks[((((icc * 7) + t) * 4 + kg) * 192 + oc) * 8 + j] = (_Float16)v;
}

// ---------------------------------------------------------------------------
// Kernel 2: transpose x (fp32 [b][ic][y][col]) -> g_xt (f16 [b][icc][y][col][ic32])
// ---------------------------------------------------------------------------
__global__ __launch_bounds__(256) void transpose_kernel(const float* __restrict__ x) {
    int id = blockIdx.x;
    int cb = id % 6;
    int y  = (id / 6) % 66;
    int b  = id / 396;
    int tid = threadIdx.x;
    int icg = tid & 3;
    int col = (tid >> 2) + cb * 64;
    if (col >= WP) return;
    const float* xb = x + (size_t)b * NIC * HPWP + y * WP + col;
#pragma unroll
    for (int icc = 0; icc < 6; icc++) {
        float v[8];
#pragma unroll
        for (int j = 0; j < 8; j++)
            v[j] = xb[(size_t)(icc * 32 + icg * 8 + j) * HPWP];
        union { f16x8 v8; _Float16 h[8]; } u;
#pragma unroll
        for (int j = 0; j < 8; j++) u.h[j] = (_Float16)v[j];
        *(f16x8*)&g_xt[((((size_t)b * 6 + icc) * 66 + y) * 322 + col) * 32 + icg * 8] = u.v8;
    }
}

// ---------------------------------------------------------------------------
// Kernel 3: MFMA implicit-GEMM conv over 7 hex taps.
// Block C-tile: 192 oc x 128 px (2 rows x 64 cols). K chunk = 32 ic.
// A (weights) from LDS slabs (conflict-free swizzled layout, 4+3 tap phases);
// B (x) read directly from global g_xt (one coalesced dwordx4 per frag, L2-hot).
// Hex taps (hy,hx): 0:(1,1) 1:(0,0) 2:(0,1) 3:(1,2) 4:(2,2) 5:(2,1) 6:(1,0)
// ---------------------------------------------------------------------------
__global__ __launch_bounds__(256, 2) void conv_kernel(
    const float* __restrict__ bias, float* __restrict__ out) {
    __shared__ __align__(16) _Float16 ws[4 * 4 * 192 * 8];   // 4 taps x kg x oc x 8 = 49.2KB

    int id = blockIdx.x;                  // 1280 blocks
    int xt5 = id % 5;
    int yt = (id / 5) % 32;
    int b  = id / 160;
    int px0 = xt5 * 64, py0 = yt * 2;

    int tid = threadIdx.x;
    int wave = tid >> 6;
    int lane = tid & 63;
    int kg = lane >> 4, n15 = lane & 15;
    int wm = wave & 1;                    // output row py0+1+wm
    int wn = wave >> 1;                   // oc half (wn*96)

    const int HY[7] = {1, 0, 0, 1, 2, 2, 1};
    const int HX[7] = {1, 0, 1, 2, 2, 1, 0};

    const _Float16* xtb = g_xt + (size_t)b * (6 * 66 * 322 * 32);

    f32x4 acc[6][4] = {};                 // [oc group][pixel group]

    for (int icc = 0; icc < 6; icc++) {
        const _Float16* xchunk = xtb + (size_t)icc * (66 * 322 * 32);
        const _Float16* kc = g_Ks + (size_t)icc * (7 * 4 * 192 * 8);

        // One slab entry (tap,kg,oc) = 8 halfs = 1 float4.
        // Phase 0 slab: 4 taps * 4 kg * 192 oc = 3072 float4s.
        // Phase 1 slab: 3 taps * 4 kg * 192 oc = 2304 float4s.
#define STAGE(SRC, N16)                                                        \
        {                                                                      \
            const _Float16* _s = (SRC);                                        \
            for (int k = 0; k < ((N16) + 255) / 256; k++) {                    \
                int idx = tid + k * 256;                                       \
                if (idx < (N16))                                               \
                    *(float4*)&ws[idx * 8] = *(const float4*)&_s[idx * 8];     \
            }                                                                  \
        }

#define COMPUTE(T, TL)                                                         \
        {                                                                      \
            int row = py0 + wm + HY[T];                                        \
            const _Float16* bp = xchunk +                                      \
                ((size_t)row * 322 + px0 + HX[T] + n15) * 32 + kg * 8;         \
            f16x8 xf[4];                                                       \
            _Pragma("unroll")                                                  \
            for (int ni = 0; ni < 4; ni++)                                     \
                xf[ni] = *(const f16x8*)(bp + ni * (16 * 32));                 \
            _Pragma("unroll")                                                  \
            for (int mi = 0; mi < 6; mi++) {                                   \
                f16x8 wf = *(const f16x8*)                                     \
                    &ws[(((TL) * 4 + kg) * 192 + wn * 96 + mi * 16 + n15) * 8];\
                _Pragma("unroll")                                              \
                for (int ni = 0; ni < 4; ni++)                                 \
                    acc[mi][ni] = __builtin_amdgcn_mfma_f32_16x16x32_f16(      \
                        wf, xf[ni], acc[mi][ni], 0, 0, 0);                     \
            }                                                                  \
        }

        // phase 0: taps 0..3
        STAGE(kc, 3072);
        __syncthreads();
        COMPUTE(0, 0); COMPUTE(1, 1); COMPUTE(2, 2); COMPUTE(3, 3);
        __syncthreads();
        // phase 1: taps 4..6
        STAGE(kc + 4 * 6144, 2304);
        __syncthreads();
        COMPUTE(4, 0); COMPUTE(5, 1); COMPUTE(6, 2);
        __syncthreads();
#undef STAGE
#undef COMPUTE
    }

    // ---- epilogue: +bias, write interior rows ----
    int yo = py0 + 1 + wm;
#pragma unroll
    for (int mi = 0; mi < 6; mi++) {
#pragma unroll
        for (int reg = 0; reg < 4; reg++) {
            int oc = wn * 96 + mi * 16 + kg * 4 + reg;
            float bv = bias[oc / 12];
            size_t base = ((size_t)(b * NOC + oc) * HP + yo) * WP + 1 + px0 + n15;
#pragma unroll
            for (int ni = 0; ni < 4; ni++)
                out[base + ni * 16] = acc[mi][ni][reg] + bv;
        }
    }
}

// ---------------------------------------------------------------------------
// Kernel 4: fill the 1-px ring via twisted-periodic gather from interior.
// ---------------------------------------------------------------------------
__global__ void border_kernel(float* __restrict__ out) {
    int tid = blockIdx.x * 256 + threadIdx.x;   // < 8*192*772 = 1185792
    int r  = tid % 772;
    int bc = tid / 772;
    int ch = bc % NOC;
    int b  = bc / NOC;
    int y, xx;
    if (r < 322)      { y = 0;  xx = r; }
    else if (r < 644) { y = 65; xx = r - 322; }
    else if (r < 708) { xx = 0;   y = r - 644 + 1; }
    else              { xx = 321; y = r - 708 + 1; }
    int t = ch % 12;
    int o12 = ch - t;
    int f = t / 6, rr = t % 6;
    int dt = (xx == 0) ? 1 : ((xx == 321) ? -1 : 0);
    int sx = (xx == 0) ? 320 : ((xx == 321) ? 1 : xx);
    int sy = (y == 0) ? 64 : ((y == 65) ? 1 : y);
    int tsrc = f * 6 + (rr + dt + 6) % 6;
    float v = out[((size_t)(b * NOC + o12 + tsrc) * HP + sy) * WP + sx];
    out[((size_t)(b * NOC + ch) * HP + y) * WP + xx] = v;
}

extern "C" void kernel_launch(void* const* d_in, const int* in_sizes, int n_in,
                              void* d_out, int out_size, void* d_ws, size_t ws_size,
                              hipStream_t stream) {
    const float* x    = (const float*)d_in[0];
    const float* w    = (const float*)d_in[1];
    const float* bias = (const float*)d_in[2];
    float* out = (float*)d_out;

    prep_kernel<<<(7 * NOC * NIC + 255) / 256, 256, 0, stream>>>(w);
    transpose_kernel<<<NB * 66 * 6, 256, 0, stream>>>(x);
    conv_kernel<<<1280, 256, 0, stream>>>(bias, out);
    border_kernel<<<(NB * NOC * 772) / 256, 256, 0, stream>>>(out);
}